// Round 1
// baseline (772.258 us; speedup 1.0000x reference)
//
#include <hip/hip_runtime.h>

typedef __bf16 bf16;
typedef __bf16 v8bf __attribute__((ext_vector_type(8)));
typedef float  v4f  __attribute__((ext_vector_type(4)));

#define L_ 4
#define B_ 32
#define N_ 512
#define D_ 256
#define H_ 8
#define F_ 1024
#define ROWS (B_*N_)   // 16384

__device__ __forceinline__ void gload16(const void* g, void* l) {
  __builtin_amdgcn_global_load_lds((__attribute__((address_space(1))) void*)g,
                                   (__attribute__((address_space(3))) void*)l,
                                   16, 0, 0);
}

// ---------------- bias = e1 @ e2^T (fp32, exact) ----------------
__global__ __launch_bounds__(256) void bias_gemm(
    const float* __restrict__ e1, const float* __restrict__ e2,
    float* __restrict__ bias) {
  __shared__ float As[16][16];
  __shared__ float Bs[16][16];
  const int tx = threadIdx.x, ty = threadIdx.y;
  const int r = blockIdx.y * 16 + ty, c = blockIdx.x * 16 + tx;
  float acc = 0.f;
  for (int k0 = 0; k0 < D_; k0 += 16) {
    As[ty][tx] = e1[r * D_ + k0 + tx];
    Bs[ty][tx] = e2[(blockIdx.x * 16 + ty) * D_ + k0 + tx];
    __syncthreads();
#pragma unroll
    for (int kk = 0; kk < 16; ++kk) acc += As[ty][kk] * Bs[tx][kk];
    __syncthreads();
  }
  bias[r * N_ + c] = acc;
}

// ---------------- weight transpose + bf16 cast: [K][N] -> [N][K] ----------------
__global__ __launch_bounds__(256) void convT(
    const float* __restrict__ W, bf16* __restrict__ Wt,
    int K, int N, size_t inL, size_t outL) {
  const int l = blockIdx.z;
  const int idx = blockIdx.x * 256 + threadIdx.x;
  if (idx < N * K) {
    const int n = idx / K, k = idx - n * K;
    Wt[l * outL + idx] = (bf16)W[l * inL + (size_t)k * N + n];
  }
}

__global__ __launch_bounds__(256) void pack_bqkv(
    const float* __restrict__ bq, const float* __restrict__ bk,
    const float* __restrict__ bv, float* __restrict__ bqkv) {
  const int i = blockIdx.x * 256 + threadIdx.x;
  if (i < L_ * 768) {
    const int l = i / 768, n = i - l * 768;
    float v = (n < 256) ? bq[l * 256 + n]
            : (n < 512) ? bk[l * 256 + n - 256]
                        : bv[l * 256 + n - 512];
    bqkv[i] = v;
  }
}

__global__ __launch_bounds__(256) void init_x(
    const float* __restrict__ src, float* __restrict__ x,
    bf16* __restrict__ xb, int n) {
  const int i = blockIdx.x * 256 + threadIdx.x;
  if (i < n) { float v = src[i]; x[i] = v; xb[i] = (bf16)v; }
}

// ---------------- bf16 MFMA GEMM: C[M][N] = A[M][K] @ Bt[N][K]^T + bias ----------------
template <int RELU, int OUTBF16>
__global__ __launch_bounds__(256, 2) void gemm_bf16k(
    const bf16* __restrict__ A, const bf16* __restrict__ Bt,
    const float* __restrict__ bias, void* __restrict__ Cout,
    int M, int N, int K) {
  __shared__ __align__(16) bf16 As[128 * 32];
  __shared__ __align__(16) bf16 Bs[128 * 32];
  const int tid  = threadIdx.x;
  const int wave = tid >> 6, lane = tid & 63;
  const int l15 = lane & 15, l4 = lane >> 4;
  const int bm = blockIdx.y * 128, bn = blockIdx.x * 128;
  const int wr = (wave >> 1) * 64, wc = (wave & 1) * 64;
  const int lrow = lane >> 2;        // 0..15 within 16-row staging slab
  const int lk   = (lane & 3) * 8;   // k-offset 0,8,16,24

  v4f acc[4][4];
#pragma unroll
  for (int m = 0; m < 4; ++m)
#pragma unroll
    for (int n = 0; n < 4; ++n) acc[m][n] = (v4f){0.f, 0.f, 0.f, 0.f};

  for (int k0 = 0; k0 < K; k0 += 32) {
#pragma unroll
    for (int c = 0; c < 2; ++c) {
      const int r = wave * 32 + c * 16;  // wave-uniform slab base
      gload16(A  + (size_t)(bm + r + lrow) * K + k0 + lk, &As[r * 32]);
      gload16(Bt + (size_t)(bn + r + lrow) * K + k0 + lk, &Bs[r * 32]);
    }
    __syncthreads();
    v8bf af[4], bfr[4];
#pragma unroll
    for (int m = 0; m < 4; ++m)
      af[m] = *(const v8bf*)&As[(wr + m * 16 + l15) * 32 + l4 * 8];
#pragma unroll
    for (int n = 0; n < 4; ++n)
      bfr[n] = *(const v8bf*)&Bs[(wc + n * 16 + l15) * 32 + l4 * 8];
#pragma unroll
    for (int m = 0; m < 4; ++m)
#pragma unroll
      for (int n = 0; n < 4; ++n)
        acc[m][n] = __builtin_amdgcn_mfma_f32_16x16x32_bf16(af[m], bfr[n], acc[m][n], 0, 0, 0);
    __syncthreads();
  }

#pragma unroll
  for (int m = 0; m < 4; ++m) {
    const int row0 = bm + wr + m * 16 + l4 * 4;
#pragma unroll
    for (int n = 0; n < 4; ++n) {
      const int col = bn + wc + n * 16 + l15;
      const float bc = bias[col];
#pragma unroll
      for (int i = 0; i < 4; ++i) {
        float v = acc[m][n][i] + bc;
        if (RELU) v = fmaxf(v, 0.f);
        const size_t idx = (size_t)(row0 + i) * N + col;
        if (OUTBF16) ((bf16*)Cout)[idx] = (bf16)v;
        else         ((float*)Cout)[idx] = v;
      }
    }
  }
}

// ---------------- fused flash attention with shared additive bias ----------------
// qkv: [B*N][768]  (q | k | v, each head h at col h*32)
// out: [B*N][256]  bf16
__global__ __launch_bounds__(256) void attn_k(
    const bf16* __restrict__ qkv, const float* __restrict__ bias,
    bf16* __restrict__ outp) {
  __shared__ __align__(16) bf16 Vt[32][512];       // V^T for this (b,h): [d][kc]
  __shared__ __align__(16) bf16 Plds[4][16][32];   // per-wave P tile
  const int tid = threadIdx.x;
  const int wave = tid >> 6, lane = tid & 63;
  const int l15 = lane & 15, l4 = lane >> 4;
  const int bh = blockIdx.y, b = bh >> 3, h = bh & 7;
  const size_t rowB = (size_t)b * N_;
  const int qbase = blockIdx.x * 64 + wave * 16;

  // stage V^T (once per block)
#pragma unroll
  for (int r = 0; r < 2; ++r) {
    const int kc = tid * 2 + r;
    const bf16* vrow = qkv + (rowB + kc) * 768 + 512 + h * 32;
#pragma unroll
    for (int d0 = 0; d0 < 32; d0 += 8) {
      v8bf vv = *(const v8bf*)(vrow + d0);
#pragma unroll
      for (int j = 0; j < 8; ++j) Vt[d0 + j][kc] = vv[j];
    }
  }
  __syncthreads();

  // Q fragment (A operand), held for all k chunks
  const v8bf qf = *(const v8bf*)(qkv + (rowB + qbase + l15) * 768 + h * 32 + l4 * 8);

  float m[4], lsum[4];
#pragma unroll
  for (int i = 0; i < 4; ++i) { m[i] = -1e30f; lsum[i] = 0.f; }
  v4f accO[2];
  accO[0] = (v4f){0.f, 0.f, 0.f, 0.f};
  accO[1] = (v4f){0.f, 0.f, 0.f, 0.f};
  const float scale = 0.17677669529663688f;  // 1/sqrt(32)

  for (int kb = 0; kb < 16; ++kb) {
    const int kbase = kb * 32;
    v4f s[2];
#pragma unroll
    for (int sub = 0; sub < 2; ++sub) {
      const v8bf kf = *(const v8bf*)(qkv + (rowB + kbase + sub * 16 + l15) * 768 + 256 + h * 32 + l4 * 8);
      v4f z = (v4f){0.f, 0.f, 0.f, 0.f};
      s[sub] = __builtin_amdgcn_mfma_f32_16x16x32_bf16(qf, kf, z, 0, 0, 0);
    }
    float cmax[4];
#pragma unroll
    for (int i = 0; i < 4; ++i) {
      const int qg = qbase + l4 * 4 + i;
      const float* bp = bias + (size_t)qg * N_ + kbase + l15;
      s[0][i] = s[0][i] * scale + bp[0];
      s[1][i] = s[1][i] * scale + bp[16];
      cmax[i] = fmaxf(s[0][i], s[1][i]);
    }
#pragma unroll
    for (int off = 1; off < 16; off <<= 1)
#pragma unroll
      for (int i = 0; i < 4; ++i)
        cmax[i] = fmaxf(cmax[i], __shfl_xor(cmax[i], off));
    float fac[4], psum[4];
#pragma unroll
    for (int i = 0; i < 4; ++i) {
      const float mn = fmaxf(m[i], cmax[i]);
      fac[i] = __expf(m[i] - mn);
      m[i] = mn;
      const float p0 = __expf(s[0][i] - mn);
      const float p1 = __expf(s[1][i] - mn);
      s[0][i] = p0; s[1][i] = p1;
      psum[i] = p0 + p1;
    }
#pragma unroll
    for (int off = 1; off < 16; off <<= 1)
#pragma unroll
      for (int i = 0; i < 4; ++i)
        psum[i] += __shfl_xor(psum[i], off);
#pragma unroll
    for (int sub = 0; sub < 2; ++sub)
#pragma unroll
      for (int i = 0; i < 4; ++i) {
        accO[sub][i] *= fac[i];
        Plds[wave][l4 * 4 + i][sub * 16 + l15] = (bf16)s[sub][i];
      }
#pragma unroll
    for (int i = 0; i < 4; ++i) lsum[i] = lsum[i] * fac[i] + psum[i];
    const v8bf pa = *(const v8bf*)&Plds[wave][l15][l4 * 8];
#pragma unroll
    for (int sub = 0; sub < 2; ++sub) {
      const v8bf vf = *(const v8bf*)&Vt[sub * 16 + l15][kbase + l4 * 8];
      accO[sub] = __builtin_amdgcn_mfma_f32_16x16x32_bf16(pa, vf, accO[sub], 0, 0, 0);
    }
  }

#pragma unroll
  for (int sub = 0; sub < 2; ++sub)
#pragma unroll
    for (int i = 0; i < 4; ++i) {
      const int qg = qbase + l4 * 4 + i;
      const int dg = h * 32 + sub * 16 + l15;
      outp[(rowB + qg) * D_ + dg] = (bf16)(accO[sub][i] / lsum[i]);
    }
}

// ---------------- residual + LayerNorm (fp32 out + bf16 out) ----------------
__global__ __launch_bounds__(256) void ln_kernel(
    const float* __restrict__ xin, const float* __restrict__ add,
    const float* __restrict__ g, const float* __restrict__ b,
    float* __restrict__ xout, bf16* __restrict__ xbout) {
  const int row = blockIdx.x, t = threadIdx.x;
  const float v = xin[(size_t)row * D_ + t] + add[(size_t)row * D_ + t];
  float s = v, ss = v * v;
#pragma unroll
  for (int off = 1; off < 64; off <<= 1) {
    s += __shfl_xor(s, off);
    ss += __shfl_xor(ss, off);
  }
  __shared__ float red[8];
  const int wv = t >> 6, ln = t & 63;
  if (ln == 0) { red[wv] = s; red[4 + wv] = ss; }
  __syncthreads();
  s = red[0] + red[1] + red[2] + red[3];
  ss = red[4] + red[5] + red[6] + red[7];
  const float mu = s * (1.f / D_);
  const float var = ss * (1.f / D_) - mu * mu;
  const float rs = rsqrtf(var + 1e-5f);
  const float o = (v - mu) * rs * g[t] + b[t];
  xout[(size_t)row * D_ + t] = o;
  xbout[(size_t)row * D_ + t] = (bf16)o;
}

extern "C" void kernel_launch(void* const* d_in, const int* in_sizes, int n_in,
                              void* d_out, int out_size, void* d_ws, size_t ws_size,
                              hipStream_t stream) {
  const float* src = (const float*)d_in[0];
  const float* e1  = (const float*)d_in[1];
  const float* e2  = (const float*)d_in[2];
  const float* Wq  = (const float*)d_in[3];
  const float* bq  = (const float*)d_in[4];
  const float* Wk  = (const float*)d_in[5];
  const float* bk  = (const float*)d_in[6];
  const float* Wv  = (const float*)d_in[7];
  const float* bv  = (const float*)d_in[8];
  const float* Wo  = (const float*)d_in[9];
  const float* bo  = (const float*)d_in[10];
  const float* W1  = (const float*)d_in[11];
  const float* b1  = (const float*)d_in[12];
  const float* W2  = (const float*)d_in[13];
  const float* b2  = (const float*)d_in[14];
  const float* g1  = (const float*)d_in[15];
  const float* be1 = (const float*)d_in[16];
  const float* g2  = (const float*)d_in[17];
  const float* be2 = (const float*)d_in[18];

  char* ws = (char*)d_ws;
  size_t off = 0;
  auto alloc = [&](size_t bytes) {
    void* p = ws + off;
    off += (bytes + 255) & ~(size_t)255;
    return p;
  };
  float* biasNN = (float*)alloc((size_t)N_ * N_ * 4);
  float* x      = (float*)alloc((size_t)ROWS * D_ * 4);
  bf16*  xb     = (bf16*) alloc((size_t)ROWS * D_ * 2);
  bf16*  attn_o = (bf16*) alloc((size_t)ROWS * D_ * 2);
  float* tmp    = (float*)alloc((size_t)ROWS * D_ * 4);
  bf16*  qkv    = (bf16*) alloc((size_t)ROWS * 1024 * 2);  // shared: qkv[768] / ffn h1[1024]
  bf16*  h1     = qkv;
  bf16*  Wqkvt  = (bf16*) alloc((size_t)L_ * 768 * 256 * 2);
  bf16*  Wot    = (bf16*) alloc((size_t)L_ * 256 * 256 * 2);
  bf16*  W1t    = (bf16*) alloc((size_t)L_ * 1024 * 256 * 2);
  bf16*  W2t    = (bf16*) alloc((size_t)L_ * 256 * 1024 * 2);
  float* bqkv   = (float*)alloc((size_t)L_ * 768 * 4);

  bias_gemm<<<dim3(32, 32), dim3(16, 16), 0, stream>>>(e1, e2, biasNN);
  convT<<<dim3(256, 1, L_), 256, 0, stream>>>(Wq, Wqkvt,          256, 256, 65536, 196608);
  convT<<<dim3(256, 1, L_), 256, 0, stream>>>(Wk, Wqkvt + 65536,  256, 256, 65536, 196608);
  convT<<<dim3(256, 1, L_), 256, 0, stream>>>(Wv, Wqkvt + 131072, 256, 256, 65536, 196608);
  convT<<<dim3(256, 1, L_), 256, 0, stream>>>(Wo, Wot,            256, 256, 65536, 65536);
  convT<<<dim3(1024, 1, L_), 256, 0, stream>>>(W1, W1t, 256, 1024, 262144, 262144);
  convT<<<dim3(1024, 1, L_), 256, 0, stream>>>(W2, W2t, 1024, 256, 262144, 262144);
  pack_bqkv<<<12, 256, 0, stream>>>(bq, bk, bv, bqkv);
  init_x<<<ROWS * D_ / 256, 256, 0, stream>>>(src, x, xb, ROWS * D_);

  for (int l = 0; l < L_; ++l) {
    gemm_bf16k<0, 1><<<dim3(6, 128), 256, 0, stream>>>(
        xb, Wqkvt + (size_t)l * 196608, bqkv + l * 768, qkv, ROWS, 768, 256);
    attn_k<<<dim3(8, B_ * H_), 256, 0, stream>>>(qkv, biasNN, attn_o);
    gemm_bf16k<0, 0><<<dim3(2, 128), 256, 0, stream>>>(
        attn_o, Wot + (size_t)l * 65536, bo + l * 256, tmp, ROWS, 256, 256);
    ln_kernel<<<ROWS, 256, 0, stream>>>(x, tmp, g1 + l * 256, be1 + l * 256, x, xb);
    gemm_bf16k<1, 1><<<dim3(8, 128), 256, 0, stream>>>(
        xb, W1t + (size_t)l * 262144, b1 + l * 1024, h1, ROWS, 1024, 256);
    gemm_bf16k<0, 0><<<dim3(2, 128), 256, 0, stream>>>(
        h1, W2t + (size_t)l * 262144, b2 + l * 256, tmp, ROWS, 256, 1024);
    float* xout = (l == L_ - 1) ? (float*)d_out : x;
    ln_kernel<<<ROWS, 256, 0, stream>>>(x, tmp, g2 + l * 256, be2 + l * 256, xout, xb);
  }
}

// Round 2
// 628.643 us; speedup vs baseline: 1.2285x; 1.2285x over previous
//
#include <hip/hip_runtime.h>

typedef __bf16 bf16;
typedef __bf16 v8bf __attribute__((ext_vector_type(8)));
typedef float  v4f  __attribute__((ext_vector_type(4)));
typedef float  v16f __attribute__((ext_vector_type(16)));
typedef unsigned short u16;
typedef u16 v8us __attribute__((ext_vector_type(8)));
typedef unsigned int v4u __attribute__((ext_vector_type(4)));

#define L_ 4
#define B_ 32
#define N_ 512
#define D_ 256
#define H_ 8
#define F_ 1024
#define ROWS (B_*N_)   // 16384

__device__ __forceinline__ void gload16(const void* g, void* l) {
  __builtin_amdgcn_global_load_lds((__attribute__((address_space(1))) void*)g,
                                   (__attribute__((address_space(3))) void*)l,
                                   16, 0, 0);
}

__device__ __forceinline__ unsigned pk_bf16(float a, float b) {
  unsigned r;
  asm("v_cvt_pk_bf16_f32 %0, %1, %2" : "=v"(r) : "v"(a), "v"(b));
  return r;
}

// ---------------- biasT[k][q] = (e2 @ e1^T) * log2(e)  (fp32) ----------------
__global__ __launch_bounds__(256) void bias_gemm(
    const float* __restrict__ e1, const float* __restrict__ e2,
    float* __restrict__ bias) {
  __shared__ float As[16][16];
  __shared__ float Bs[16][16];
  const int tx = threadIdx.x, ty = threadIdx.y;
  const int r = blockIdx.y * 16 + ty, c = blockIdx.x * 16 + tx;
  float acc = 0.f;
  for (int k0 = 0; k0 < D_; k0 += 16) {
    As[ty][tx] = e1[r * D_ + k0 + tx];
    Bs[ty][tx] = e2[(blockIdx.x * 16 + ty) * D_ + k0 + tx];
    __syncthreads();
#pragma unroll
    for (int kk = 0; kk < 16; ++kk) acc += As[ty][kk] * Bs[tx][kk];
    __syncthreads();
  }
  bias[r * N_ + c] = acc * 1.4426950408889634f;
}

// ---------------- tiled weight transpose + bf16 cast: [K][N] -> [N][K] ----------------
__global__ __launch_bounds__(256) void convT(
    const float* __restrict__ W, bf16* __restrict__ Wt,
    int K, int N, size_t inL, size_t outL) {
  __shared__ float t[32][33];
  const int l = blockIdx.z;
  const int k0 = blockIdx.y * 32, n0 = blockIdx.x * 32;
  const int r = threadIdx.x >> 5, c = threadIdx.x & 31;
#pragma unroll
  for (int i = 0; i < 4; ++i)
    t[r + 8 * i][c] = W[l * inL + (size_t)(k0 + r + 8 * i) * N + n0 + c];
  __syncthreads();
#pragma unroll
  for (int i = 0; i < 4; ++i)
    Wt[l * outL + (size_t)(n0 + r + 8 * i) * K + k0 + c] = (bf16)t[c][r + 8 * i];
}

__global__ __launch_bounds__(256) void pack_bqkv(
    const float* __restrict__ bq, const float* __restrict__ bk,
    const float* __restrict__ bv, float* __restrict__ bqkv) {
  const int i = blockIdx.x * 256 + threadIdx.x;
  if (i < L_ * 768) {
    const int l = i / 768, n = i - l * 768;
    float v = (n < 256) ? bq[l * 256 + n]
            : (n < 512) ? bk[l * 256 + n - 256]
                        : bv[l * 256 + n - 512];
    bqkv[i] = v;
  }
}

__global__ __launch_bounds__(256) void init_x(
    const float* __restrict__ src, float* __restrict__ x,
    bf16* __restrict__ xb, int n) {
  const int i = blockIdx.x * 256 + threadIdx.x;
  if (i < n) { float v = src[i]; x[i] = v; xb[i] = (bf16)v; }
}

// ---------------- bf16 MFMA GEMM: C[M][N] = A[M][K] @ Bt[N][K]^T + bias ----------------
template <int RELU, int OUTBF16>
__global__ __launch_bounds__(256, 2) void gemm_bf16k(
    const bf16* __restrict__ A, const bf16* __restrict__ Bt,
    const float* __restrict__ bias, void* __restrict__ Cout,
    int M, int N, int K) {
  __shared__ __align__(16) bf16 As[128 * 32];
  __shared__ __align__(16) bf16 Bs[128 * 32];
  const int tid  = threadIdx.x;
  const int wave = tid >> 6, lane = tid & 63;
  const int l15 = lane & 15, l4 = lane >> 4;
  const int bm = blockIdx.y * 128, bn = blockIdx.x * 128;
  const int wr = (wave >> 1) * 64, wc = (wave & 1) * 64;
  const int lrow = lane >> 2;
  const int lk   = (lane & 3) * 8;

  v4f acc[4][4];
#pragma unroll
  for (int m = 0; m < 4; ++m)
#pragma unroll
    for (int n = 0; n < 4; ++n) acc[m][n] = (v4f){0.f, 0.f, 0.f, 0.f};

  for (int k0 = 0; k0 < K; k0 += 32) {
#pragma unroll
    for (int c = 0; c < 2; ++c) {
      const int r = wave * 32 + c * 16;
      gload16(A  + (size_t)(bm + r + lrow) * K + k0 + lk, &As[r * 32]);
      gload16(Bt + (size_t)(bn + r + lrow) * K + k0 + lk, &Bs[r * 32]);
    }
    __syncthreads();
    v8bf af[4], bfr[4];
#pragma unroll
    for (int m = 0; m < 4; ++m)
      af[m] = *(const v8bf*)&As[(wr + m * 16 + l15) * 32 + l4 * 8];
#pragma unroll
    for (int n = 0; n < 4; ++n)
      bfr[n] = *(const v8bf*)&Bs[(wc + n * 16 + l15) * 32 + l4 * 8];
#pragma unroll
    for (int m = 0; m < 4; ++m)
#pragma unroll
      for (int n = 0; n < 4; ++n)
        acc[m][n] = __builtin_amdgcn_mfma_f32_16x16x32_bf16(af[m], bfr[n], acc[m][n], 0, 0, 0);
    __syncthreads();
  }

#pragma unroll
  for (int m = 0; m < 4; ++m) {
    const int row0 = bm + wr + m * 16 + l4 * 4;
#pragma unroll
    for (int n = 0; n < 4; ++n) {
      const int col = bn + wc + n * 16 + l15;
      const float bc = bias[col];
#pragma unroll
      for (int i = 0; i < 4; ++i) {
        float v = acc[m][n][i] + bc;
        if (RELU) v = fmaxf(v, 0.f);
        const size_t idx = (size_t)(row0 + i) * N + col;
        if (OUTBF16) ((bf16*)Cout)[idx] = (bf16)v;
        else         ((float*)Cout)[idx] = v;
      }
    }
  }
}

// ---------------- fused flash attention, swapped-operand 32x32 ----------------
// qkv: [B*N][768] bf16 (q|k|v), biasT: [k][q] fp32 pre-scaled by log2e
// out: [B*N][256] bf16
#define VTS 520   // Vt row stride in ushorts (1040B: 16B-aligned, bank-balanced)
__global__ __launch_bounds__(256, 4) void attn_k(
    const bf16* __restrict__ qkv, const float* __restrict__ biasT,
    bf16* __restrict__ outp) {
  __shared__ u16 Vt[32 * VTS];   // V^T: [d][kc]
  const int tid = threadIdx.x;
  const int wave = tid >> 6, lane = tid & 63;
  const int l31 = lane & 31, hi = lane >> 5;
  const int bh = blockIdx.y, b = bh >> 3, h = bh & 7;
  const u16* base = (const u16*)qkv + (size_t)b * N_ * 768;
  const int qb = blockIdx.x * 128 + wave * 32;

  // ---- stage V^T (once per block): thread t packs rows 2t,2t+1 ----
  {
    const u16* vb = base + 512 + h * 32;
    const u16* p0 = vb + (size_t)(2 * tid) * 768;
    const u16* p1 = p0 + 768;
#pragma unroll
    for (int d0 = 0; d0 < 32; d0 += 8) {
      v8us a = *(const v8us*)(p0 + d0);
      v8us c = *(const v8us*)(p1 + d0);
#pragma unroll
      for (int j = 0; j < 8; ++j) {
        unsigned u = (unsigned)a[j] | ((unsigned)c[j] << 16);
        *(unsigned*)&Vt[(d0 + j) * VTS + tid * 2] = u;
      }
    }
  }
  __syncthreads();

  // ---- Q fragments (B operand), held all chunks ----
  const u16* qrow = base + (size_t)(qb + l31) * 768 + h * 32;
  const v8bf qf0 = *(const v8bf*)(qrow + hi * 8);
  const v8bf qf1 = *(const v8bf*)(qrow + 16 + hi * 8);
  const u16* kvb = base + 256 + h * 32;

  const float SC2 = 0.17677669529663688f * 1.4426950408889634f;
  float mrun = -1e30f, lsum = 0.f;
  v16f accO = {0.f,0.f,0.f,0.f,0.f,0.f,0.f,0.f,0.f,0.f,0.f,0.f,0.f,0.f,0.f,0.f};

  for (int kb = 0; kb < 16; ++kb) {
    const int kbase = kb * 32;
    const u16* kptr = kvb + (size_t)(kbase + l31) * 768;
    const v8bf ka0 = *(const v8bf*)(kptr + hi * 8);
    const v8bf ka1 = *(const v8bf*)(kptr + 16 + hi * 8);

    v16f st = {0.f,0.f,0.f,0.f,0.f,0.f,0.f,0.f,0.f,0.f,0.f,0.f,0.f,0.f,0.f,0.f};
    st = __builtin_amdgcn_mfma_f32_32x32x16_bf16(ka0, qf0, st, 0, 0, 0);
    st = __builtin_amdgcn_mfma_f32_32x32x16_bf16(ka1, qf1, st, 0, 0, 0);

    // logits (base-2 domain): p = st*scale*log2e + biasT
    float p[16];
#pragma unroll
    for (int r = 0; r < 16; ++r) {
      const int kr = (r & 3) + 8 * (r >> 2) + 4 * hi;
      p[r] = st[r] * SC2 + biasT[(size_t)(kbase + kr) * N_ + qb + l31];
    }
    // max tree (16 in-reg + cross-hi)
    float c8[8], c4[4], c2[2];
#pragma unroll
    for (int r = 0; r < 8; ++r) c8[r] = fmaxf(p[r], p[r + 8]);
#pragma unroll
    for (int r = 0; r < 4; ++r) c4[r] = fmaxf(c8[r], c8[r + 4]);
    c2[0] = fmaxf(c4[0], c4[2]); c2[1] = fmaxf(c4[1], c4[3]);
    float cmax = fmaxf(c2[0], c2[1]);
    cmax = fmaxf(cmax, __shfl_xor(cmax, 32));
    const float mn = fmaxf(mrun, cmax);
    const float fac = exp2f(mrun - mn);
    mrun = mn;
#pragma unroll
    for (int r = 0; r < 16; ++r) p[r] = exp2f(p[r] - mn);
    // sum tree
    float s8[8], s4[4], s2[2];
#pragma unroll
    for (int r = 0; r < 8; ++r) s8[r] = p[r] + p[r + 8];
#pragma unroll
    for (int r = 0; r < 4; ++r) s4[r] = s8[r] + s8[r + 4];
    s2[0] = s4[0] + s4[2]; s2[1] = s4[1] + s4[3];
    float psum = s2[0] + s2[1];
    psum += __shfl_xor(psum, 32);
    lsum = lsum * fac + psum;

    // P -> bf16, redistribute into PV B-fragments (k-major per lane)
    unsigned u[8], x[8];
#pragma unroll
    for (int t = 0; t < 8; ++t) {
      u[t] = pk_bf16(p[2 * t], p[2 * t + 1]);
      x[t] = (unsigned)__shfl_xor((int)u[t], 32);
    }
    v4u b0 = (v4u){hi ? x[2] : u[0], hi ? x[3] : u[1], hi ? u[2] : x[0], hi ? u[3] : x[1]};
    v4u b1 = (v4u){hi ? x[6] : u[4], hi ? x[7] : u[5], hi ? u[6] : x[4], hi ? u[7] : x[5]};
    union { v4u u; v8bf h; } cv0, cv1;
    cv0.u = b0; cv1.u = b1;

    const v8bf va0 = *(const v8bf*)&Vt[l31 * VTS + kbase + hi * 8];
    const v8bf va1 = *(const v8bf*)&Vt[l31 * VTS + kbase + 16 + hi * 8];
#pragma unroll
    for (int r = 0; r < 16; ++r) accO[r] *= fac;
    accO = __builtin_amdgcn_mfma_f32_32x32x16_bf16(va0, cv0.h, accO, 0, 0, 0);
    accO = __builtin_amdgcn_mfma_f32_32x32x16_bf16(va1, cv1.h, accO, 0, 0, 0);
  }

  // ---- epilogue: O^T[d][q] regs -> out[q][h*32+d] ----
  const float inv = 1.0f / lsum;
  u16* orow = (u16*)outp + (size_t)(b * N_ + qb + l31) * D_ + h * 32 + 4 * hi;
#pragma unroll
  for (int g = 0; g < 4; ++g) {
    uint2 w;
    w.x = pk_bf16(accO[4 * g] * inv, accO[4 * g + 1] * inv);
    w.y = pk_bf16(accO[4 * g + 2] * inv, accO[4 * g + 3] * inv);
    *(uint2*)(orow + 8 * g) = w;
  }
}

// ---------------- residual + LayerNorm (fp32 out + bf16 out) ----------------
__global__ __launch_bounds__(256) void ln_kernel(
    const float* __restrict__ xin, const float* __restrict__ add,
    const float* __restrict__ g, const float* __restrict__ b,
    float* __restrict__ xout, bf16* __restrict__ xbout) {
  const int row = blockIdx.x, t = threadIdx.x;
  const float v = xin[(size_t)row * D_ + t] + add[(size_t)row * D_ + t];
  float s = v, ss = v * v;
#pragma unroll
  for (int off = 1; off < 64; off <<= 1) {
    s += __shfl_xor(s, off);
    ss += __shfl_xor(ss, off);
  }
  __shared__ float red[8];
  const int wv = t >> 6, ln = t & 63;
  if (ln == 0) { red[wv] = s; red[4 + wv] = ss; }
  __syncthreads();
  s = red[0] + red[1] + red[2] + red[3];
  ss = red[4] + red[5] + red[6] + red[7];
  const float mu = s * (1.f / D_);
  const float var = ss * (1.f / D_) - mu * mu;
  const float rs = rsqrtf(var + 1e-5f);
  const float o = (v - mu) * rs * g[t] + b[t];
  xout[(size_t)row * D_ + t] = o;
  xbout[(size_t)row * D_ + t] = (bf16)o;
}

extern "C" void kernel_launch(void* const* d_in, const int* in_sizes, int n_in,
                              void* d_out, int out_size, void* d_ws, size_t ws_size,
                              hipStream_t stream) {
  const float* src = (const float*)d_in[0];
  const float* e1  = (const float*)d_in[1];
  const float* e2  = (const float*)d_in[2];
  const float* Wq  = (const float*)d_in[3];
  const float* bq  = (const float*)d_in[4];
  const float* Wk  = (const float*)d_in[5];
  const float* bk  = (const float*)d_in[6];
  const float* Wv  = (const float*)d_in[7];
  const float* bv  = (const float*)d_in[8];
  const float* Wo  = (const float*)d_in[9];
  const float* bo  = (const float*)d_in[10];
  const float* W1  = (const float*)d_in[11];
  const float* b1  = (const float*)d_in[12];
  const float* W2  = (const float*)d_in[13];
  const float* b2  = (const float*)d_in[14];
  const float* g1  = (const float*)d_in[15];
  const float* be1 = (const float*)d_in[16];
  const float* g2  = (const float*)d_in[17];
  const float* be2 = (const float*)d_in[18];

  char* ws = (char*)d_ws;
  size_t off = 0;
  auto alloc = [&](size_t bytes) {
    void* p = ws + off;
    off += (bytes + 255) & ~(size_t)255;
    return p;
  };
  float* biasT  = (float*)alloc((size_t)N_ * N_ * 4);
  float* x      = (float*)alloc((size_t)ROWS * D_ * 4);
  bf16*  xb     = (bf16*) alloc((size_t)ROWS * D_ * 2);
  bf16*  attn_o = (bf16*) alloc((size_t)ROWS * D_ * 2);
  float* tmp    = (float*)alloc((size_t)ROWS * D_ * 4);
  bf16*  qkv    = (bf16*) alloc((size_t)ROWS * 1024 * 2);  // shared: qkv[768] / ffn h1[1024]
  bf16*  h1     = qkv;
  bf16*  Wqkvt  = (bf16*) alloc((size_t)L_ * 768 * 256 * 2);
  bf16*  Wot    = (bf16*) alloc((size_t)L_ * 256 * 256 * 2);
  bf16*  W1t    = (bf16*) alloc((size_t)L_ * 1024 * 256 * 2);
  bf16*  W2t    = (bf16*) alloc((size_t)L_ * 256 * 1024 * 2);
  float* bqkv   = (float*)alloc((size_t)L_ * 768 * 4);

  // biasT[k][q] = e2[k].e1[q] * log2e
  bias_gemm<<<dim3(32, 32), dim3(16, 16), 0, stream>>>(e2, e1, biasT);
  convT<<<dim3(8, 8, L_),  256, 0, stream>>>(Wq, Wqkvt,          256, 256, 65536, 196608);
  convT<<<dim3(8, 8, L_),  256, 0, stream>>>(Wk, Wqkvt + 65536,  256, 256, 65536, 196608);
  convT<<<dim3(8, 8, L_),  256, 0, stream>>>(Wv, Wqkvt + 131072, 256, 256, 65536, 196608);
  convT<<<dim3(8, 8, L_),  256, 0, stream>>>(Wo, Wot,            256, 256, 65536, 65536);
  convT<<<dim3(32, 8, L_), 256, 0, stream>>>(W1, W1t, 256, 1024, 262144, 262144);
  convT<<<dim3(8, 32, L_), 256, 0, stream>>>(W2, W2t, 1024, 256, 262144, 262144);
  pack_bqkv<<<12, 256, 0, stream>>>(bq, bk, bv, bqkv);
  init_x<<<ROWS * D_ / 256, 256, 0, stream>>>(src, x, xb, ROWS * D_);

  for (int l = 0; l < L_; ++l) {
    gemm_bf16k<0, 1><<<dim3(6, 128), 256, 0, stream>>>(
        xb, Wqkvt + (size_t)l * 196608, bqkv + l * 768, qkv, ROWS, 768, 256);
    attn_k<<<dim3(4, B_ * H_), 256, 0, stream>>>(qkv, biasT, attn_o);
    gemm_bf16k<0, 0><<<dim3(2, 128), 256, 0, stream>>>(
        attn_o, Wot + (size_t)l * 65536, bo + l * 256, tmp, ROWS, 256, 256);
    ln_kernel<<<ROWS, 256, 0, stream>>>(x, tmp, g1 + l * 256, be1 + l * 256, x, xb);
    gemm_bf16k<1, 1><<<dim3(8, 128), 256, 0, stream>>>(
        xb, W1t + (size_t)l * 262144, b1 + l * 1024, h1, ROWS, 1024, 256);
    gemm_bf16k<0, 0><<<dim3(2, 128), 256, 0, stream>>>(
        h1, W2t + (size_t)l * 262144, b2 + l * 256, tmp, ROWS, 256, 1024);
    float* xout = (l == L_ - 1) ? (float*)d_out : x;
    ln_kernel<<<ROWS, 256, 0, stream>>>(x, tmp, g2 + l * 256, be2 + l * 256, xout, xb);
  }
}

// Round 3
// 588.433 us; speedup vs baseline: 1.3124x; 1.0683x over previous
//
#include <hip/hip_runtime.h>

typedef __bf16 bf16;
typedef __bf16 v8bf __attribute__((ext_vector_type(8)));
typedef float  v4f  __attribute__((ext_vector_type(4)));
typedef float  v16f __attribute__((ext_vector_type(16)));
typedef unsigned short u16;
typedef u16 v8us __attribute__((ext_vector_type(8)));
typedef unsigned int v4u __attribute__((ext_vector_type(4)));

#define L_ 4
#define B_ 32
#define N_ 512
#define D_ 256
#define H_ 8
#define F_ 1024
#define ROWS (B_*N_)   // 16384

__device__ __forceinline__ void gload16(const void* g, void* l) {
  __builtin_amdgcn_global_load_lds((__attribute__((address_space(1))) void*)g,
                                   (__attribute__((address_space(3))) void*)l,
                                   16, 0, 0);
}

__device__ __forceinline__ unsigned pk_bf16(float a, float b) {
  unsigned r;
  asm("v_cvt_pk_bf16_f32 %0, %1, %2" : "=v"(r) : "v"(a), "v"(b));
  return r;
}

#define EXP2(x) __builtin_amdgcn_exp2f(x)

// ---------------- biasT[k][q] = (e2 @ e1^T) * log2(e)  (fp32) ----------------
__global__ __launch_bounds__(256) void bias_gemm(
    const float* __restrict__ e1, const float* __restrict__ e2,
    float* __restrict__ bias) {
  __shared__ float As[16][16];
  __shared__ float Bs[16][16];
  const int tx = threadIdx.x, ty = threadIdx.y;
  const int r = blockIdx.y * 16 + ty, c = blockIdx.x * 16 + tx;
  float acc = 0.f;
  for (int k0 = 0; k0 < D_; k0 += 16) {
    As[ty][tx] = e1[r * D_ + k0 + tx];
    Bs[ty][tx] = e2[(blockIdx.x * 16 + ty) * D_ + k0 + tx];
    __syncthreads();
#pragma unroll
    for (int kk = 0; kk < 16; ++kk) acc += As[ty][kk] * Bs[tx][kk];
    __syncthreads();
  }
  bias[r * N_ + c] = acc * 1.4426950408889634f;
}

// ---------------- m[q] = max_k biasT[k][q] ----------------
__global__ __launch_bounds__(256) void colmax(
    const float* __restrict__ bias, float* __restrict__ m) {
  __shared__ float part[8][32];
  const int tid = threadIdx.x;
  const int qi = tid & 31, chunk = tid >> 5;
  const int q = blockIdx.x * 32 + qi;
  float mx = -1e30f;
#pragma unroll 8
  for (int k = chunk * 64; k < chunk * 64 + 64; ++k)
    mx = fmaxf(mx, bias[(size_t)k * N_ + q]);
  part[chunk][qi] = mx;
  __syncthreads();
  if (tid < 32) {
    float r = part[0][tid];
#pragma unroll
    for (int j = 1; j < 8; ++j) r = fmaxf(r, part[j][tid]);
    m[blockIdx.x * 32 + tid] = r;
  }
}

// ---------------- biasT[k][q] -= m[q]  (float4) ----------------
__global__ __launch_bounds__(256) void subm(
    float* __restrict__ bias, const float* __restrict__ m) {
  const int idx = blockIdx.x * 256 + threadIdx.x;  // over 65536 float4
  float4 v = ((float4*)bias)[idx];
  const float4 mm = *(const float4*)&m[(idx * 4) & (N_ - 1)];
  v.x -= mm.x; v.y -= mm.y; v.z -= mm.z; v.w -= mm.w;
  ((float4*)bias)[idx] = v;
}

// ---------------- tiled weight transpose + bf16 cast: [K][N] -> [N][K] ----------------
__global__ __launch_bounds__(256) void convT(
    const float* __restrict__ W, bf16* __restrict__ Wt,
    int K, int N, size_t inL, size_t outL) {
  __shared__ float t[32][33];
  const int l = blockIdx.z;
  const int k0 = blockIdx.y * 32, n0 = blockIdx.x * 32;
  const int r = threadIdx.x >> 5, c = threadIdx.x & 31;
#pragma unroll
  for (int i = 0; i < 4; ++i)
    t[r + 8 * i][c] = W[l * inL + (size_t)(k0 + r + 8 * i) * N + n0 + c];
  __syncthreads();
#pragma unroll
  for (int i = 0; i < 4; ++i)
    Wt[l * outL + (size_t)(n0 + r + 8 * i) * K + k0 + c] = (bf16)t[c][r + 8 * i];
}

__global__ __launch_bounds__(256) void pack_bqkv(
    const float* __restrict__ bq, const float* __restrict__ bk,
    const float* __restrict__ bv, float* __restrict__ bqkv) {
  const int i = blockIdx.x * 256 + threadIdx.x;
  if (i < L_ * 768) {
    const int l = i / 768, n = i - l * 768;
    float v = (n < 256) ? bq[l * 256 + n]
            : (n < 512) ? bk[l * 256 + n - 256]
                        : bv[l * 256 + n - 512];
    bqkv[i] = v;
  }
}

__global__ __launch_bounds__(256) void init_x(
    const float* __restrict__ src, float* __restrict__ x,
    bf16* __restrict__ xb) {
  const int i = blockIdx.x * 256 + threadIdx.x;  // float4 index
  float4 v = ((const float4*)src)[i];
  ((float4*)x)[i] = v;
  uint2 w;
  w.x = pk_bf16(v.x, v.y);
  w.y = pk_bf16(v.z, v.w);
  ((uint2*)xb)[i] = w;
}

// ---------------- bf16 MFMA GEMM: C[M][N] = A[M][K] @ Bt[N][K]^T + bias ----------------
// tile BM x 128; 4 waves
template <int BM, int RELU, int OUTBF16>
__global__ __launch_bounds__(256, 2) void gemm_bf16k(
    const bf16* __restrict__ A, const bf16* __restrict__ Bt,
    const float* __restrict__ bias, void* __restrict__ Cout,
    int M, int N, int K) {
  constexpr int MR = BM / 32;        // frag rows per wave
  constexpr int NSLAB = BM / 16 + 8; // 16-row staging slabs (A + B)
  __shared__ __align__(16) bf16 As[BM * 32];
  __shared__ __align__(16) bf16 Bs[128 * 32];
  const int tid  = threadIdx.x;
  const int wave = tid >> 6, lane = tid & 63;
  const int l15 = lane & 15, l4 = lane >> 4;
  const int bm = blockIdx.y * BM, bn = blockIdx.x * 128;
  const int wr = (wave >> 1) * (BM / 2), wc = (wave & 1) * 64;
  const int lrow = lane >> 2;
  const int lk   = (lane & 3) * 8;

  v4f acc[MR][4];
#pragma unroll
  for (int m = 0; m < MR; ++m)
#pragma unroll
    for (int n = 0; n < 4; ++n) acc[m][n] = (v4f){0.f, 0.f, 0.f, 0.f};

  for (int k0 = 0; k0 < K; k0 += 32) {
#pragma unroll
    for (int s = wave; s < NSLAB; s += 4) {
      if (s < BM / 16)
        gload16(A + (size_t)(bm + s * 16 + lrow) * K + k0 + lk, &As[s * 16 * 32]);
      else {
        const int sb = s - BM / 16;
        gload16(Bt + (size_t)(bn + sb * 16 + lrow) * K + k0 + lk, &Bs[sb * 16 * 32]);
      }
    }
    __syncthreads();
    v8bf af[MR], bfr[4];
#pragma unroll
    for (int m = 0; m < MR; ++m)
      af[m] = *(const v8bf*)&As[(wr + m * 16 + l15) * 32 + l4 * 8];
#pragma unroll
    for (int n = 0; n < 4; ++n)
      bfr[n] = *(const v8bf*)&Bs[(wc + n * 16 + l15) * 32 + l4 * 8];
#pragma unroll
    for (int m = 0; m < MR; ++m)
#pragma unroll
      for (int n = 0; n < 4; ++n)
        acc[m][n] = __builtin_amdgcn_mfma_f32_16x16x32_bf16(af[m], bfr[n], acc[m][n], 0, 0, 0);
    __syncthreads();
  }

#pragma unroll
  for (int m = 0; m < MR; ++m) {
    const int row0 = bm + wr + m * 16 + l4 * 4;
#pragma unroll
    for (int n = 0; n < 4; ++n) {
      const int col = bn + wc + n * 16 + l15;
      const float bc = bias[col];
#pragma unroll
      for (int i = 0; i < 4; ++i) {
        float v = acc[m][n][i] + bc;
        if (RELU) v = fmaxf(v, 0.f);
        const size_t idx = (size_t)(row0 + i) * N + col;
        if (OUTBF16) ((bf16*)Cout)[idx] = (bf16)v;
        else         ((float*)Cout)[idx] = v;
      }
    }
  }
}

// ---------------- fused flash attention, swapped-operand 32x32, fixed normalizer ----------------
// qkv: [B*N][768] bf16 (q|k|v); biasS: [k][q] fp32 = bias*log2e - max_k(bias*log2e)
// out: [B*N][256] bf16
#define VTS 520
__global__ __launch_bounds__(256, 4) void attn_k(
    const bf16* __restrict__ qkv, const float* __restrict__ biasS,
    bf16* __restrict__ outp) {
  __shared__ u16 Vt[32 * VTS];   // V^T: [d][kc]
  const int tid = threadIdx.x;
  const int wave = tid >> 6, lane = tid & 63;
  const int l31 = lane & 31, hi = lane >> 5;
  const int bh = blockIdx.y, b = bh >> 3, h = bh & 7;
  const u16* base = (const u16*)qkv + (size_t)b * N_ * 768;
  const int qb = blockIdx.x * 128 + wave * 32;

  // ---- stage V^T (once per block): thread t packs rows 2t,2t+1 ----
  {
    const u16* vb = base + 512 + h * 32;
    const u16* p0 = vb + (size_t)(2 * tid) * 768;
    const u16* p1 = p0 + 768;
#pragma unroll
    for (int d0 = 0; d0 < 32; d0 += 8) {
      v8us a = *(const v8us*)(p0 + d0);
      v8us c = *(const v8us*)(p1 + d0);
#pragma unroll
      for (int j = 0; j < 8; ++j) {
        unsigned u = (unsigned)a[j] | ((unsigned)c[j] << 16);
        *(unsigned*)&Vt[(d0 + j) * VTS + tid * 2] = u;
      }
    }
  }
  __syncthreads();

  // ---- Q fragments (B operand), held all chunks ----
  const u16* qrow = base + (size_t)(qb + l31) * 768 + h * 32;
  const v8bf qf0 = *(const v8bf*)(qrow + hi * 8);
  const v8bf qf1 = *(const v8bf*)(qrow + 16 + hi * 8);
  const u16* kvb = base + 256 + h * 32;

  const float SC2 = 0.17677669529663688f * 1.4426950408889634f;
  float lsum = 0.f;
  v16f accO = {0.f,0.f,0.f,0.f,0.f,0.f,0.f,0.f,0.f,0.f,0.f,0.f,0.f,0.f,0.f,0.f};

  for (int kb = 0; kb < 16; ++kb) {
    const int kbase = kb * 32;
    const u16* kptr = kvb + (size_t)(kbase + l31) * 768;
    const v8bf ka0 = *(const v8bf*)(kptr + hi * 8);
    const v8bf ka1 = *(const v8bf*)(kptr + 16 + hi * 8);

    v16f st = {0.f,0.f,0.f,0.f,0.f,0.f,0.f,0.f,0.f,0.f,0.f,0.f,0.f,0.f,0.f,0.f};
    st = __builtin_amdgcn_mfma_f32_32x32x16_bf16(ka0, qf0, st, 0, 0, 0);
    st = __builtin_amdgcn_mfma_f32_32x32x16_bf16(ka1, qf1, st, 0, 0, 0);

    // p = exp2(st*scale*log2e + biasS)   (biasS pre-max-subtracted)
    float p[16];
#pragma unroll
    for (int r = 0; r < 16; ++r) {
      const int kr = (r & 3) + 8 * (r >> 2) + 4 * hi;
      p[r] = EXP2(st[r] * SC2 + biasS[(size_t)(kbase + kr) * N_ + qb + l31]);
    }
    // lane-local partial sum (cross-hi fixed up once at the end)
    float s8[8], s4[4];
#pragma unroll
    for (int r = 0; r < 8; ++r) s8[r] = p[r] + p[r + 8];
#pragma unroll
    for (int r = 0; r < 4; ++r) s4[r] = s8[r] + s8[r + 4];
    lsum += (s4[0] + s4[2]) + (s4[1] + s4[3]);

    // P -> bf16, redistribute into PV B-fragments (k-major per lane)
    unsigned u[8], x[8];
#pragma unroll
    for (int t = 0; t < 8; ++t) {
      u[t] = pk_bf16(p[2 * t], p[2 * t + 1]);
      x[t] = (unsigned)__shfl_xor((int)u[t], 32);
    }
    v4u b0 = (v4u){hi ? x[2] : u[0], hi ? x[3] : u[1], hi ? u[2] : x[0], hi ? u[3] : x[1]};
    v4u b1 = (v4u){hi ? x[6] : u[4], hi ? x[7] : u[5], hi ? u[6] : x[4], hi ? u[7] : x[5]};
    union { v4u u; v8bf h; } cv0, cv1;
    cv0.u = b0; cv1.u = b1;

    const v8bf va0 = *(const v8bf*)&Vt[l31 * VTS + kbase + hi * 8];
    const v8bf va1 = *(const v8bf*)&Vt[l31 * VTS + kbase + 16 + hi * 8];
    accO = __builtin_amdgcn_mfma_f32_32x32x16_bf16(va0, cv0.h, accO, 0, 0, 0);
    accO = __builtin_amdgcn_mfma_f32_32x32x16_bf16(va1, cv1.h, accO, 0, 0, 0);
  }

  lsum += __shfl_xor(lsum, 32);

  // ---- epilogue: O^T[d][q] regs -> out[q][h*32+d] ----
  const float inv = 1.0f / lsum;
  u16* orow = (u16*)outp + (size_t)(b * N_ + qb + l31) * D_ + h * 32 + 4 * hi;
#pragma unroll
  for (int g = 0; g < 4; ++g) {
    uint2 w;
    w.x = pk_bf16(accO[4 * g] * inv, accO[4 * g + 1] * inv);
    w.y = pk_bf16(accO[4 * g + 2] * inv, accO[4 * g + 3] * inv);
    *(uint2*)(orow + 8 * g) = w;
  }
}

// ---------------- residual + LayerNorm: 1 wave per row, 4 rows/block ----------------
__global__ __launch_bounds__(256) void ln_kernel(
    const float* __restrict__ xin, const float* __restrict__ add,
    const float* __restrict__ g, const float* __restrict__ b,
    float* __restrict__ xout, bf16* __restrict__ xbout) {
  const int wv = threadIdx.x >> 6, ln = threadIdx.x & 63;
  const size_t row = blockIdx.x * 4 + wv;
  const size_t o4 = row * D_ + ln * 4;
  const float4 xi = *(const float4*)&xin[o4];
  const float4 ad = *(const float4*)&add[o4];
  float4 v;
  v.x = xi.x + ad.x; v.y = xi.y + ad.y; v.z = xi.z + ad.z; v.w = xi.w + ad.w;
  float s  = (v.x + v.y) + (v.z + v.w);
  float ss = (v.x * v.x + v.y * v.y) + (v.z * v.z + v.w * v.w);
#pragma unroll
  for (int off = 1; off < 64; off <<= 1) {
    s  += __shfl_xor(s, off);
    ss += __shfl_xor(ss, off);
  }
  const float mu = s * (1.f / D_);
  const float var = ss * (1.f / D_) - mu * mu;
  const float rs = rsqrtf(var + 1e-5f);
  const float4 gg = *(const float4*)&g[ln * 4];
  const float4 bb = *(const float4*)&b[ln * 4];
  float4 o;
  o.x = (v.x - mu) * rs * gg.x + bb.x;
  o.y = (v.y - mu) * rs * gg.y + bb.y;
  o.z = (v.z - mu) * rs * gg.z + bb.z;
  o.w = (v.w - mu) * rs * gg.w + bb.w;
  *(float4*)&xout[o4] = o;
  uint2 w;
  w.x = pk_bf16(o.x, o.y);
  w.y = pk_bf16(o.z, o.w);
  *(uint2*)&xbout[o4] = w;
}

extern "C" void kernel_launch(void* const* d_in, const int* in_sizes, int n_in,
                              void* d_out, int out_size, void* d_ws, size_t ws_size,
                              hipStream_t stream) {
  const float* src = (const float*)d_in[0];
  const float* e1  = (const float*)d_in[1];
  const float* e2  = (const float*)d_in[2];
  const float* Wq  = (const float*)d_in[3];
  const float* bq  = (const float*)d_in[4];
  const float* Wk  = (const float*)d_in[5];
  const float* bk  = (const float*)d_in[6];
  const float* Wv  = (const float*)d_in[7];
  const float* bv  = (const float*)d_in[8];
  const float* Wo  = (const float*)d_in[9];
  const float* bo  = (const float*)d_in[10];
  const float* W1  = (const float*)d_in[11];
  const float* b1  = (const float*)d_in[12];
  const float* W2  = (const float*)d_in[13];
  const float* b2  = (const float*)d_in[14];
  const float* g1  = (const float*)d_in[15];
  const float* be1 = (const float*)d_in[16];
  const float* g2  = (const float*)d_in[17];
  const float* be2 = (const float*)d_in[18];

  char* ws = (char*)d_ws;
  size_t off = 0;
  auto alloc = [&](size_t bytes) {
    void* p = ws + off;
    off += (bytes + 255) & ~(size_t)255;
    return p;
  };
  float* biasT  = (float*)alloc((size_t)N_ * N_ * 4);
  float* mq     = (float*)alloc((size_t)N_ * 4);
  float* x      = (float*)alloc((size_t)ROWS * D_ * 4);
  bf16*  xb     = (bf16*) alloc((size_t)ROWS * D_ * 2);
  bf16*  attn_o = (bf16*) alloc((size_t)ROWS * D_ * 2);
  float* tmp    = (float*)alloc((size_t)ROWS * D_ * 4);
  bf16*  qkv    = (bf16*) alloc((size_t)ROWS * 1024 * 2);  // shared: qkv[768] / ffn h1[1024]
  bf16*  h1     = qkv;
  bf16*  Wqkvt  = (bf16*) alloc((size_t)L_ * 768 * 256 * 2);
  bf16*  Wot    = (bf16*) alloc((size_t)L_ * 256 * 256 * 2);
  bf16*  W1t    = (bf16*) alloc((size_t)L_ * 1024 * 256 * 2);
  bf16*  W2t    = (bf16*) alloc((size_t)L_ * 256 * 1024 * 2);
  float* bqkv   = (float*)alloc((size_t)L_ * 768 * 4);

  // biasT[k][q] = e2[k].e1[q] * log2e, then subtract per-q column max
  bias_gemm<<<dim3(32, 32), dim3(16, 16), 0, stream>>>(e2, e1, biasT);
  colmax<<<16, 256, 0, stream>>>(biasT, mq);
  subm<<<256, 256, 0, stream>>>(biasT, mq);
  convT<<<dim3(8, 8, L_),  256, 0, stream>>>(Wq, Wqkvt,          256, 256, 65536, 196608);
  convT<<<dim3(8, 8, L_),  256, 0, stream>>>(Wk, Wqkvt + 65536,  256, 256, 65536, 196608);
  convT<<<dim3(8, 8, L_),  256, 0, stream>>>(Wv, Wqkvt + 131072, 256, 256, 65536, 196608);
  convT<<<dim3(8, 8, L_),  256, 0, stream>>>(Wo, Wot,            256, 256, 65536, 65536);
  convT<<<dim3(32, 8, L_), 256, 0, stream>>>(W1, W1t, 256, 1024, 262144, 262144);
  convT<<<dim3(8, 32, L_), 256, 0, stream>>>(W2, W2t, 1024, 256, 262144, 262144);
  pack_bqkv<<<12, 256, 0, stream>>>(bq, bk, bv, bqkv);
  init_x<<<ROWS * D_ / 1024, 256, 0, stream>>>(src, x, xb);

  for (int l = 0; l < L_; ++l) {
    gemm_bf16k<128, 0, 1><<<dim3(6, 128), 256, 0, stream>>>(
        xb, Wqkvt + (size_t)l * 196608, bqkv + l * 768, qkv, ROWS, 768, 256);
    attn_k<<<dim3(4, B_ * H_), 256, 0, stream>>>(qkv, biasT, attn_o);
    gemm_bf16k<64, 0, 0><<<dim3(2, 256), 256, 0, stream>>>(
        attn_o, Wot + (size_t)l * 65536, bo + l * 256, tmp, ROWS, 256, 256);
    ln_kernel<<<ROWS / 4, 256, 0, stream>>>(x, tmp, g1 + l * 256, be1 + l * 256, x, xb);
    gemm_bf16k<128, 1, 1><<<dim3(8, 128), 256, 0, stream>>>(
        xb, W1t + (size_t)l * 262144, b1 + l * 1024, h1, ROWS, 1024, 256);
    gemm_bf16k<64, 0, 0><<<dim3(2, 256), 256, 0, stream>>>(
        h1, W2t + (size_t)l * 262144, b2 + l * 256, tmp, ROWS, 256, 1024);
    float* xout = (l == L_ - 1) ? (float*)d_out : x;
    ln_kernel<<<ROWS / 4, 256, 0, stream>>>(x, tmp, g2 + l * 256, be2 + l * 256, xout, xb);
  }
}